// Round 1
// baseline (85.282 us; speedup 1.0000x reference)
//
#include <hip/hip_runtime.h>
#include <math.h>

#define B_ 8
#define C_ 64
#define K_ 32
#define HW_ 16384
#define CHUNK_ 128
#define NCHUNK_ 128          // HW_ / CHUNK_
#define LD1 68               // padded LDS row stride (floats): 16B-aligned, shifts banks by 4/row
#define PIX_ 512
#define NEG_SLOPE_ 0.1f

// ws layout:
//   [0, 16MB)            float partial[B_][NCHUNK_][C_][C_]
//   [16MB, 16MB+64KB)    int   idx[B_][C_][K_]

__global__ __launch_bounds__(256) void corr_partial_kernel(
    const float* __restrict__ LR, const float* __restrict__ HR,
    float* __restrict__ partial)
{
    __shared__ float lrS[CHUNK_][LD1];
    __shared__ float hrS[CHUNK_][LD1];
    const int blk = blockIdx.x;
    const int b = blk / NCHUNK_;
    const int chunk = blk % NCHUNK_;
    const int n0 = chunk * CHUNK_;
    const int t = threadIdx.x;

    // stage transposed [n][c]: coalesced global reads, conflict-free LDS writes (stride 68 -> +4 banks/step)
    for (int i = t; i < C_ * CHUNK_; i += 256) {
        const int c = i / CHUNK_;
        const int n = i % CHUNK_;
        lrS[n][c] = LR[(size_t)(b * C_ + c) * HW_ + n0 + n];
        hrS[n][c] = HR[(size_t)(b * C_ + c) * HW_ + n0 + n];
    }
    __syncthreads();

    // 16x16 thread grid, each thread owns a 4c x 4d tile
    const int cq = t >> 4;
    const int dq = t & 15;
    const int c0 = cq * 4, d0 = dq * 4;
    float acc[4][4] = {};
    for (int n = 0; n < CHUNK_; ++n) {
        const float4 lv = *reinterpret_cast<const float4*>(&lrS[n][c0]);
        const float4 hv = *reinterpret_cast<const float4*>(&hrS[n][d0]);
        const float l[4] = {lv.x, lv.y, lv.z, lv.w};
        const float h[4] = {hv.x, hv.y, hv.z, hv.w};
        #pragma unroll
        for (int i = 0; i < 4; ++i)
            #pragma unroll
            for (int j = 0; j < 4; ++j)
                acc[i][j] = fmaf(l[i], h[j], acc[i][j]);
    }
    float* P = partial + (size_t)(b * NCHUNK_ + chunk) * (C_ * C_);
    #pragma unroll
    for (int i = 0; i < 4; ++i) {
        const float4 v = make_float4(acc[i][0], acc[i][1], acc[i][2], acc[i][3]);
        *reinterpret_cast<float4*>(&P[(c0 + i) * C_ + d0]) = v;
    }
}

__global__ __launch_bounds__(64) void topk_kernel(
    const float* __restrict__ partial, int* __restrict__ idxb)
{
    __shared__ double vals[C_];
    const int blk = blockIdx.x;     // b*64 + c
    const int b = blk >> 6;
    const int c = blk & 63;
    const int d = threadIdx.x;

    double acc = 0.0;
    for (int k = 0; k < NCHUNK_; ++k)
        acc += (double)partial[(size_t)(b * NCHUNK_ + k) * (C_ * C_) + c * C_ + d];
    vals[d] = acc;
    __syncthreads();

    const double vd = acc;
    int r = 0;
    for (int j = 0; j < C_; ++j) {
        const double vj = vals[j];
        r += (int)((vj > vd) || (vj == vd && j < d));   // stable descending rank
    }
    if (r < K_) idxb[blk * K_ + r] = d;
}

__global__ __launch_bounds__(256) void fusion_kernel(
    const float* __restrict__ HR, const float* __restrict__ LR,
    const int* __restrict__ idxb,
    const float* __restrict__ w1, const float* __restrict__ b1,
    const float* __restrict__ w2, const float* __restrict__ b2,
    float* __restrict__ out)
{
    __shared__ float hrS[C_][PIX_];     // 128 KB
    __shared__ int   idxS[C_][K_];      // 8 KB
    __shared__ float w1S[K_ + 1];

    const int b  = blockIdx.x >> 5;           // 32 tiles per batch
    const int p0 = (blockIdx.x & 31) * PIX_;
    const int t  = threadIdx.x;

    const float* HRb = HR + (size_t)b * C_ * HW_;
    for (int i = t; i < C_ * (PIX_ / 4); i += 256) {
        const int ch = i >> 7;                // PIX_/4 = 128 float4 per row
        const int c4 = (i & 127) * 4;
        *reinterpret_cast<float4*>(&hrS[ch][c4]) =
            *reinterpret_cast<const float4*>(&HRb[(size_t)ch * HW_ + p0 + c4]);
    }
    for (int i = t; i < C_ * K_; i += 256)
        idxS[i >> 5][i & 31] = idxb[b * C_ * K_ + i];
    if (t <= K_) w1S[t] = w1[t];
    __syncthreads();

    const float w10 = w1S[0];
    const float b1v = b1[0], w2v = w2[0], b2v = b2[0];
    const int px = t * 2;

    for (int c = 0; c < C_; ++c) {
        float mx0 = -1e30f, mx1 = -1e30f, a0 = 0.f, a1 = 0.f;
        #pragma unroll
        for (int k = 0; k < K_; ++k) {
            const int ch = idxS[c][k];
            const float2 g = *reinterpret_cast<const float2*>(&hrS[ch][px]);
            mx0 = fmaxf(mx0, g.x);
            mx1 = fmaxf(mx1, g.y);
            const float w = w1S[k + 1];
            a0 = fmaf(w, g.x, a0);
            a1 = fmaf(w, g.y, a1);
        }
        const float2 lr = *reinterpret_cast<const float2*>(
            &LR[(size_t)(b * C_ + c) * HW_ + p0 + px]);
        float f0 = fmaf(w10, lr.x, a0) + b1v;
        float f1 = fmaf(w10, lr.y, a1) + b1v;
        f0 = f0 >= 0.f ? f0 : NEG_SLOPE_ * f0;
        f1 = f1 >= 0.f ? f1 : NEG_SLOPE_ * f1;
        f0 = fmaf(w2v, f0, b2v);
        f1 = fmaf(w2v, f1, b2v);
        const float wt0 = 1.f / (1.f + expf(-mx0));
        const float wt1 = 1.f / (1.f + expf(-mx1));
        float2 o;
        o.x = f0 * (1.f + wt0);
        o.y = f1 * (1.f + wt1);
        *reinterpret_cast<float2*>(&out[(size_t)(b * C_ + c) * HW_ + p0 + px]) = o;
    }
}

extern "C" void kernel_launch(void* const* d_in, const int* in_sizes, int n_in,
                              void* d_out, int out_size, void* d_ws, size_t ws_size,
                              hipStream_t stream)
{
    const float* HR = (const float*)d_in[0];
    const float* LR = (const float*)d_in[1];
    const float* w1 = (const float*)d_in[2];
    const float* b1 = (const float*)d_in[3];
    const float* w2 = (const float*)d_in[4];
    const float* b2 = (const float*)d_in[5];
    float* out = (float*)d_out;

    float* partial = (float*)d_ws;
    int* idxb = (int*)((char*)d_ws + (size_t)B_ * NCHUNK_ * C_ * C_ * sizeof(float));

    corr_partial_kernel<<<B_ * NCHUNK_, 256, 0, stream>>>(LR, HR, partial);
    topk_kernel<<<B_ * C_, 64, 0, stream>>>(partial, idxb);
    fusion_kernel<<<B_ * 32, 256, 0, stream>>>(HR, LR, idxb, w1, b1, w2, b2, out);
}

// Round 2
// 81.129 us; speedup vs baseline: 1.0512x; 1.0512x over previous
//
#include <hip/hip_runtime.h>
#include <math.h>

#define B_ 8
#define C_ 64
#define K_ 32
#define HW_ 16384
#define CHUNK_ 128
#define NCHUNKOUT_ 64        // 64 partial slabs, 2 chunks accumulated per block
#define LD1 68               // padded LDS row stride (floats)
#define CG_ 8                // channels per fusion block
#define NEG_SLOPE_ 0.1f

// ws layout:
//   [0, 8MB)        float partial[B_][NCHUNKOUT_][C_][C_]
//   [8MB, 10MB)     float tab[B_][8 cgroups][64 d][16]   (8 w, then 8 bias)

__global__ __launch_bounds__(256) void corr_partial_kernel(
    const float* __restrict__ LR, const float* __restrict__ HR,
    float* __restrict__ partial)
{
    __shared__ float lrS[CHUNK_][LD1];
    __shared__ float hrS[CHUNK_][LD1];
    const int blk = blockIdx.x;
    const int b = blk >> 6;            // / 64
    const int j = blk & 63;
    const int t = threadIdx.x;

    const int cq = t >> 4;
    const int dq = t & 15;
    const int c0 = cq * 4, d0 = dq * 4;
    float acc[4][4] = {};

    for (int half = 0; half < 2; ++half) {
        const int n0 = (j * 2 + half) * CHUNK_;
        if (half) __syncthreads();     // protect LDS before restage
        for (int i = t; i < C_ * CHUNK_; i += 256) {
            const int c = i / CHUNK_;
            const int n = i % CHUNK_;
            lrS[n][c] = LR[(size_t)(b * C_ + c) * HW_ + n0 + n];
            hrS[n][c] = HR[(size_t)(b * C_ + c) * HW_ + n0 + n];
        }
        __syncthreads();

        for (int n = 0; n < CHUNK_; ++n) {
            const float4 lv = *reinterpret_cast<const float4*>(&lrS[n][c0]);
            const float4 hv = *reinterpret_cast<const float4*>(&hrS[n][d0]);
            const float l[4] = {lv.x, lv.y, lv.z, lv.w};
            const float h[4] = {hv.x, hv.y, hv.z, hv.w};
            #pragma unroll
            for (int i = 0; i < 4; ++i)
                #pragma unroll
                for (int k = 0; k < 4; ++k)
                    acc[i][k] = fmaf(l[i], h[k], acc[i][k]);
        }
    }

    float* P = partial + (size_t)(b * NCHUNKOUT_ + j) * (C_ * C_);
    #pragma unroll
    for (int i = 0; i < 4; ++i) {
        const float4 v = make_float4(acc[i][0], acc[i][1], acc[i][2], acc[i][3]);
        *reinterpret_cast<float4*>(&P[(c0 + i) * C_ + d0]) = v;
    }
}

// Reduce partials (f64, deterministic), rank channels per (b,c) like lax.top_k
// (stable descending), and emit dense weight/bias tables for the fusion sweep.
__global__ __launch_bounds__(64) void rank_kernel(
    const float* __restrict__ partial, const float* __restrict__ w1,
    float* __restrict__ tab)
{
    __shared__ double vals[C_];
    const int blk = blockIdx.x;     // b*64 + c
    const int b = blk >> 6;
    const int c = blk & 63;
    const int d = threadIdx.x;

    double acc = 0.0;
    for (int k = 0; k < NCHUNKOUT_; ++k)
        acc += (double)partial[(size_t)(b * NCHUNKOUT_ + k) * (C_ * C_) + c * C_ + d];
    vals[d] = acc;
    __syncthreads();

    int r = 0;
    for (int jj = 0; jj < C_; ++jj) {
        const double vj = vals[jj];
        r += (int)((vj > acc) || (vj == acc && jj < d));   // stable descending rank
    }

    float wv = 0.f, bv = -1e30f;
    if (r < K_) { wv = w1[r + 1]; bv = 0.f; }
    const int cg = c >> 3, ci = c & 7;
    float* te = tab + ((size_t)((b * 8 + cg) * 64 + d)) * 16;
    te[ci] = wv;
    te[8 + ci] = bv;
}

// Dense fusion: per thread 8 channels x 4 px, sweep all 64 HR channels.
// weighted sum via dense w (zeros for absent), masked max via bias add.
__global__ __launch_bounds__(256, 4) void fusion_dense_kernel(
    const float* __restrict__ HR, const float* __restrict__ LR,
    const float* __restrict__ tab,
    const float* __restrict__ w1, const float* __restrict__ b1,
    const float* __restrict__ w2, const float* __restrict__ b2,
    float* __restrict__ out)
{
    // de-swizzle: the 8 cgroup-blocks of one (b,pxtile) share bid%8 -> same XCD
    const int bid = blockIdx.x;
    const int low = bid & 7;
    const int q = bid >> 3;
    const int cg = q >> 4;
    const int gkey = (q & 15) * 8 + low;     // b*16 + pxtile
    const int b = gkey >> 4;
    const int pxt = gkey & 15;
    const int px0 = pxt * 1024 + threadIdx.x * 4;

    const float* HRb = HR + (size_t)b * C_ * HW_ + px0;
    const float* trow = tab + (size_t)(b * 8 + cg) * 64 * 16;

    float acc[CG_][4];
    float mx[CG_][4];
    #pragma unroll
    for (int ci = 0; ci < CG_; ++ci)
        #pragma unroll
        for (int p = 0; p < 4; ++p) { acc[ci][p] = 0.f; mx[ci][p] = -1e30f; }

    #pragma unroll 4
    for (int d = 0; d < C_; ++d) {
        const float4 hv = *reinterpret_cast<const float4*>(&HRb[(size_t)d * HW_]);
        const float h[4] = {hv.x, hv.y, hv.z, hv.w};
        const float* te = trow + d * 16;
        #pragma unroll
        for (int ci = 0; ci < CG_; ++ci) {
            const float w = te[ci];        // wave-uniform -> s_load
            const float bs = te[8 + ci];   // wave-uniform -> s_load
            #pragma unroll
            for (int p = 0; p < 4; ++p) {
                acc[ci][p] = fmaf(h[p], w, acc[ci][p]);
                mx[ci][p] = fmaxf(mx[ci][p], h[p] + bs);
            }
        }
    }

    const float w10 = w1[0];
    const float b1v = b1[0], w2v = w2[0], b2v = b2[0];
    const float* LRb = LR + (size_t)b * C_ * HW_ + px0;
    float* outb = out + (size_t)b * C_ * HW_ + px0;

    #pragma unroll
    for (int ci = 0; ci < CG_; ++ci) {
        const int c = cg * CG_ + ci;
        const float4 lr = *reinterpret_cast<const float4*>(&LRb[(size_t)c * HW_]);
        const float l[4] = {lr.x, lr.y, lr.z, lr.w};
        float o[4];
        #pragma unroll
        for (int p = 0; p < 4; ++p) {
            float f = fmaf(w10, l[p], acc[ci][p]) + b1v;
            f = f >= 0.f ? f : NEG_SLOPE_ * f;
            f = fmaf(w2v, f, b2v);
            const float s = 1.f / (1.f + expf(-mx[ci][p]));
            o[p] = f * (1.f + s);
        }
        *reinterpret_cast<float4*>(&outb[(size_t)c * HW_]) =
            make_float4(o[0], o[1], o[2], o[3]);
    }
}

extern "C" void kernel_launch(void* const* d_in, const int* in_sizes, int n_in,
                              void* d_out, int out_size, void* d_ws, size_t ws_size,
                              hipStream_t stream)
{
    const float* HR = (const float*)d_in[0];
    const float* LR = (const float*)d_in[1];
    const float* w1 = (const float*)d_in[2];
    const float* b1 = (const float*)d_in[3];
    const float* w2 = (const float*)d_in[4];
    const float* b2 = (const float*)d_in[5];
    float* out = (float*)d_out;

    float* partial = (float*)d_ws;
    float* tab = (float*)((char*)d_ws + (size_t)B_ * NCHUNKOUT_ * C_ * C_ * sizeof(float));

    corr_partial_kernel<<<B_ * NCHUNKOUT_, 256, 0, stream>>>(LR, HR, partial);
    rank_kernel<<<B_ * C_, 64, 0, stream>>>(partial, w1, tab);
    fusion_dense_kernel<<<B_ * 16 * 8, 256, 0, stream>>>(HR, LR, tab, w1, b1, w2, b2, out);
}